// Round 9
// baseline (735.672 us; speedup 1.0000x reference)
//
#include <hip/hip_runtime.h>

typedef _Float16 half8 __attribute__((ext_vector_type(8)));
typedef float    float4v __attribute__((ext_vector_type(4)));

#define NQ 8
#define KCODES 4096
#define DIMS 128
#define BATCH 8
#define SEQ 4096
#define ROWS (BATCH*SEQ)            // 32768
#define TM 64                       // rows per block
#define NBLK (ROWS/TM)              // 512
#define RESPAD 132                  // res row stride (floats), 16B-aligned
#define OUT_ELEMS (BATCH*DIMS*SEQ)  // 4194304
#define IDX_ELEMS (BATCH*SEQ*NQ)    // 262144
#define LOSS_DIV (1.0f/33554432.0f) // 1/(Q*B*N*D)
#define FRAG_HALVES ((size_t)NQ*4*256*64*8)   // per hi/lo: 4.19M f16 = 8 MB
#define QSTRIDE ((size_t)256*4*64*8)          // halves per q = 524288
#define TILE_HALVES (4*64*8)                  // halves per tile = 2048 (4 KB)

// ---------------- prep: c_sq[q][k] = sum_d cb^2 ----------------
__global__ void prep_csq(const float* __restrict__ cb, float* __restrict__ csq) {
    int c = blockIdx.x * 256 + threadIdx.x;   // q*4096+k
    const float4* p = (const float4*)(cb + (size_t)c * DIMS);
    float s = 0.f;
#pragma unroll
    for (int i = 0; i < 32; ++i) {
        float4 v = p[i];
        s += v.x * v.x + v.y * v.y + v.z * v.z + v.w * v.w;
    }
    csq[c] = s;
}

// ---------------- prep: codebook -> f16 hi/lo MFMA B-fragments ----------------
// mfma_f32_16x16x32_f16 B-operand: lane l holds B[k=(l>>4)*8+j][n=l&15], j=0..7.
// Layout (kb-contiguous per tile): g = ((q*256+nt)*4+kb)*64+lane, frag at g*8.
// One tile = uniform base + lane*16B voffset + imm offsets {0,1024,2048,3072}.
__global__ void prep_frags(const float* __restrict__ cb, _Float16* __restrict__ bhi,
                           _Float16* __restrict__ blo, float* __restrict__ loss_accum) {
    int g = blockIdx.x * 256 + threadIdx.x;   // 524288 total
    if (g == 0) loss_accum[0] = 0.f;
    int lane = g & 63;
    int kb   = (g >> 6) & 3;
    int nt   = (g >> 8) & 255;
    int q    = g >> 16;
    int code = nt * 16 + (lane & 15);
    int k0   = kb * 32 + ((lane >> 4) * 8);
    const float* src = cb + ((size_t)q * KCODES + code) * DIMS + k0;
    float4 v0 = *(const float4*)(src);
    float4 v1 = *(const float4*)(src + 4);
    float f[8] = { v0.x, v0.y, v0.z, v0.w, v1.x, v1.y, v1.z, v1.w };
    half8 h, l;
#pragma unroll
    for (int j = 0; j < 8; ++j) {
        _Float16 hh = (_Float16)f[j];
        h[j] = hh;
        l[j] = (_Float16)(f[j] - (float)hh);
    }
    *(half8*)(bhi + (size_t)g * 8) = h;
    *(half8*)(blo + (size_t)g * 8) = l;
}

// ---------------- main RVQ kernel ----------------
// Uniform tile base + divergent laneoff: compiles to saddr-form loads with
// immediate kb offsets (kb*512 halves = 1024 B, fits 13-bit signed).
__device__ __forceinline__ void load_b2(const _Float16* __restrict__ pH,
                                        const _Float16* __restrict__ pL,
                                        int laneoff,
                                        half8 (&bh)[4], half8 (&bl)[4]) {
#pragma unroll
    for (int kb = 0; kb < 4; ++kb) {
        bh[kb] = *(const half8*)(pH + kb * 512 + laneoff);
        bl[kb] = *(const half8*)(pL + kb * 512 + laneoff);
    }
}

// Term-major MFMA schedule: hh(kb0..3), lh(kb0..3), hl(kb0..3), mt innermost.
// Same-acc dependence distance = 4 MFMAs everywhere; bl first consumed after
// 32 MFMAs. Both bh and bl full-tile double-buffered by the caller (no WAR).
// s_setprio(1) over the MFMA region stabilizes anti-phase wave arbitration.
__device__ __forceinline__ void compute_tile(float fidx,
                                             const half8 (&ahi)[4][4], const half8 (&alo)[4][4],
                                             const half8 (&bh)[4], const half8 (&bl)[4], float cs,
                                             float (&bestd)[4][4], float (&besti)[4][4]) {
    float nh = -0.5f * cs;
    float4v acc[4];
#pragma unroll
    for (int mt = 0; mt < 4; ++mt) { acc[mt][0] = nh; acc[mt][1] = nh; acc[mt][2] = nh; acc[mt][3] = nh; }
    __builtin_amdgcn_s_setprio(1);
#pragma unroll
    for (int kb = 0; kb < 4; ++kb)
#pragma unroll
        for (int mt = 0; mt < 4; ++mt)
            acc[mt] = __builtin_amdgcn_mfma_f32_16x16x32_f16(ahi[mt][kb], bh[kb], acc[mt], 0, 0, 0);
#pragma unroll
    for (int kb = 0; kb < 4; ++kb)
#pragma unroll
        for (int mt = 0; mt < 4; ++mt)
            acc[mt] = __builtin_amdgcn_mfma_f32_16x16x32_f16(alo[mt][kb], bh[kb], acc[mt], 0, 0, 0);
#pragma unroll
    for (int kb = 0; kb < 4; ++kb)
#pragma unroll
        for (int mt = 0; mt < 4; ++mt)
            acc[mt] = __builtin_amdgcn_mfma_f32_16x16x32_f16(ahi[mt][kb], bl[kb], acc[mt], 0, 0, 0);
    __builtin_amdgcn_s_setprio(0);

    // key = dot - csq/2; argMAX == argmin(csq - 2*dot); strict > keeps first index
#pragma unroll
    for (int mt = 0; mt < 4; ++mt)
#pragma unroll
        for (int r = 0; r < 4; ++r) {
            float key = acc[mt][r];
            if (key > bestd[mt][r]) { bestd[mt][r] = key; besti[mt][r] = fidx; }
        }
}

__launch_bounds__(256, 2)
__global__ void rvq_main(const float* __restrict__ x, const float* __restrict__ cb,
                         const _Float16* __restrict__ bhi, const _Float16* __restrict__ blo,
                         const float* __restrict__ csq,
                         float* __restrict__ out, float* __restrict__ loss_accum) {
    __shared__ float res[TM][RESPAD];   // residual, row-major fp32
    __shared__ float wbd[4][TM];        // per-wave best key
    __shared__ float wbi[4][TM];        // per-wave best idx (as float)
    __shared__ float fbin[TM];          // final best idx per row
    __shared__ float red[256];

    int tid  = threadIdx.x;
    int lane = tid & 63;
    int wv   = __builtin_amdgcn_readfirstlane(tid >> 6);   // provably wave-uniform
    int r0   = blockIdx.x * TM;
    int b    = r0 >> 12;                // / SEQ
    int n0   = r0 & (SEQ - 1);
    const float* xb = x + (size_t)b * DIMS * SEQ + n0;
    float fcol   = (float)(lane & 15);
    int   laneoff = lane * 8;           // halves: lane*16 B voffset
    int   c15     = lane & 15;          // csq voffset element

    // load x[b][d][n0..n0+63] into res[n][d]
    {
        int d = tid >> 1, half = (tid & 1) * 32;
        const float* src = xb + (size_t)d * SEQ + half;
#pragma unroll
        for (int t4 = 0; t4 < 8; ++t4) {
            float4 v = *(const float4*)(src + t4 * 4);
            res[half + t4 * 4 + 0][d] = v.x;
            res[half + t4 * 4 + 1][d] = v.y;
            res[half + t4 * 4 + 2][d] = v.z;
            res[half + t4 * 4 + 3][d] = v.w;
        }
    }

    float lossacc = 0.f;

    for (int q = 0; q < NQ; ++q) {
        __syncthreads();   // res stable

        // build A fragments (hi/lo) in registers/AGPRs
        half8 ahi[4][4], alo[4][4];
#pragma unroll
        for (int mt = 0; mt < 4; ++mt)
#pragma unroll
        for (int kb = 0; kb < 4; ++kb) {
            int row = mt * 16 + (lane & 15);
            int k0  = kb * 32 + (lane >> 4) * 8;
            float4 v0 = *(const float4*)&res[row][k0];
            float4 v1 = *(const float4*)&res[row][k0 + 4];
            float f[8] = { v0.x, v0.y, v0.z, v0.w, v1.x, v1.y, v1.z, v1.w };
            half8 h, l;
#pragma unroll
            for (int j = 0; j < 8; ++j) {
                _Float16 hh = (_Float16)f[j];
                h[j] = hh;
                l[j] = (_Float16)(f[j] - (float)hh);
            }
            ahi[mt][kb] = h;
            alo[mt][kb] = l;
        }

        // uniform (SGPR) tile bases for this wave's 64-tile range
        const _Float16* pHbase = bhi + (size_t)q * QSTRIDE + (size_t)wv * 64 * TILE_HALVES;
        const _Float16* pLbase = blo + (size_t)q * QSTRIDE + (size_t)wv * 64 * TILE_HALVES;
        const float*    pCbase = csq + q * KCODES + wv * 1024;

        float bestd[4][4], besti[4][4];
#pragma unroll
        for (int mt = 0; mt < 4; ++mt)
#pragma unroll
        for (int r = 0; r < 4; ++r) { bestd[mt][r] = -3.4e38f; besti[mt][r] = 0.f; }

        half8 bh0[4], bl0[4], bh1[4], bl1[4];
        float cs0, cs1;
        const _Float16* pH = pHbase;
        const _Float16* pL = pLbase;
        const float*    pC = pCbase;
        float ftile = (float)(wv * 1024) + fcol;   // fidx of tile 0

        load_b2(pH, pL, laneoff, bh0, bl0);
        cs0 = pC[c15];

        // Phase stagger: odd waves burn ~40 throwaway MFMAs so their MFMA phase
        // anti-aligns with even waves' VALU phase. accD is preamble-local.
        if (wv & 1) {
            float4v accD[4];
            float nh = -0.5f * cs0;
#pragma unroll
            for (int mt = 0; mt < 4; ++mt) { accD[mt][0] = nh; accD[mt][1] = nh; accD[mt][2] = nh; accD[mt][3] = nh; }
            __builtin_amdgcn_s_setprio(1);
#pragma unroll
            for (int kb = 0; kb < 4; ++kb)
#pragma unroll
                for (int mt = 0; mt < 4; ++mt)
                    accD[mt] = __builtin_amdgcn_mfma_f32_16x16x32_f16(ahi[mt][kb], bh0[kb], accD[mt], 0, 0, 0);
#pragma unroll
            for (int kb = 0; kb < 4; ++kb)
#pragma unroll
                for (int mt = 0; mt < 4; ++mt)
                    accD[mt] = __builtin_amdgcn_mfma_f32_16x16x32_f16(alo[mt][kb], bh0[kb], accD[mt], 0, 0, 0);
#pragma unroll
            for (int kb = 0; kb < 2; ++kb)
#pragma unroll
                for (int mt = 0; mt < 4; ++mt)
                    accD[mt] = __builtin_amdgcn_mfma_f32_16x16x32_f16(ahi[mt][kb], bl0[kb], accD[mt], 0, 0, 0);
            __builtin_amdgcn_s_setprio(0);
            lossacc = fmaf(0.0f, (accD[0][0] + accD[1][0]) + (accD[2][0] + accD[3][0]), lossacc);
        }

        for (int i = 0; i < 64; i += 2) {
            // prefetch tile i+1 (base pH+TILE_HALVES, scalar-stepped)
            load_b2(pH + TILE_HALVES, pL + TILE_HALVES, laneoff, bh1, bl1);
            cs1 = pC[c15 + 16];
            compute_tile(ftile, ahi, alo, bh0, bl0, cs0, bestd, besti);
            // prefetch tile i+2 (uniform wrap on the last iteration: no OOB)
            const _Float16* pHn = (i == 62) ? pHbase : pH + 2 * TILE_HALVES;
            const _Float16* pLn = (i == 62) ? pLbase : pL + 2 * TILE_HALVES;
            const float*    pCn = (i == 62) ? pCbase : pC + 32;
            load_b2(pHn, pLn, laneoff, bh0, bl0);
            cs0 = pCn[c15];
            compute_tile(ftile + 16.f, ahi, alo, bh1, bl1, cs1, bestd, besti);
            pH = pHn; pL = pLn; pC = pCn;
            ftile += 32.f;
        }

        // reduce across the 16 lanes sharing each row (low 4 lane bits)
#pragma unroll
        for (int mask = 1; mask <= 8; mask <<= 1) {
#pragma unroll
            for (int mt = 0; mt < 4; ++mt)
#pragma unroll
            for (int r = 0; r < 4; ++r) {
                float od = __shfl_xor(bestd[mt][r], mask, 64);
                float oi = __shfl_xor(besti[mt][r], mask, 64);
                if (od > bestd[mt][r] || (od == bestd[mt][r] && oi < besti[mt][r])) {
                    bestd[mt][r] = od;
                    besti[mt][r] = oi;
                }
            }
        }
        if ((lane & 15) == 0) {
            int qd = lane >> 4;
#pragma unroll
            for (int mt = 0; mt < 4; ++mt)
#pragma unroll
            for (int r = 0; r < 4; ++r) {
                int row = mt * 16 + qd * 4 + r;
                wbd[wv][row] = bestd[mt][r];
                wbi[wv][row] = besti[mt][r];
            }
        }
        __syncthreads();

        // cross-wave reduce (waves cover ascending code ranges; tie -> smaller idx)
        if (tid < TM) {
            float bd = wbd[0][tid], bi = wbi[0][tid];
#pragma unroll
            for (int w = 1; w < 4; ++w) {
                float dd = wbd[w][tid], ii = wbi[w][tid];
                if (dd > bd || (dd == bd && ii < bi)) { bd = dd; bi = ii; }
            }
            fbin[tid] = bi;
            out[OUT_ELEMS + (size_t)(r0 + tid) * NQ + q] = bi;   // index output (float)
        }
        __syncthreads();

        // residual update + commitment-loss accumulation
        {
            int row = tid >> 2, j = tid & 3;
            int bi = (int)fbin[row];
            const float* cv = cb + ((size_t)q * KCODES + bi) * DIMS + j * 4;
            float* rp = &res[row][j * 4];
#pragma unroll
            for (int t = 0; t < 8; ++t) {
                float4 c4 = *(const float4*)(cv + t * 16);
                float4 r4 = *(const float4*)(rp + t * 16);
                r4.x -= c4.x; lossacc = fmaf(r4.x, r4.x, lossacc);
                r4.y -= c4.y; lossacc = fmaf(r4.y, r4.y, lossacc);
                r4.z -= c4.z; lossacc = fmaf(r4.z, r4.z, lossacc);
                r4.w -= c4.w; lossacc = fmaf(r4.w, r4.w, lossacc);
                *(float4*)(rp + t * 16) = r4;
            }
        }
    }

    // loss reduction
    __syncthreads();
    red[tid] = lossacc;
    __syncthreads();
    for (int s = 128; s > 0; s >>= 1) {
        if (tid < s) red[tid] += red[tid + s];
        __syncthreads();
    }
    if (tid == 0) atomicAdd(loss_accum, red[0]);

    // quantized output: out = x - final_residual
    {
        int d = tid >> 1, half = (tid & 1) * 32;
        const float* src = xb + (size_t)d * SEQ + half;
        float* dst = out + (size_t)b * DIMS * SEQ + (size_t)d * SEQ + n0 + half;
#pragma unroll
        for (int t4 = 0; t4 < 8; ++t4) {
            float4 v = *(const float4*)(src + t4 * 4);
            v.x -= res[half + t4 * 4 + 0][d];
            v.y -= res[half + t4 * 4 + 1][d];
            v.z -= res[half + t4 * 4 + 2][d];
            v.w -= res[half + t4 * 4 + 3][d];
            *(float4*)(dst + t4 * 4) = v;
        }
    }
}

__global__ void finish_loss(const float* __restrict__ loss_accum, float* __restrict__ out) {
    out[OUT_ELEMS + IDX_ELEMS] = loss_accum[0] * LOSS_DIV;
}

extern "C" void kernel_launch(void* const* d_in, const int* in_sizes, int n_in,
                              void* d_out, int out_size, void* d_ws, size_t ws_size,
                              hipStream_t stream) {
    const float* x  = (const float*)d_in[0];
    const float* cb = (const float*)d_in[1];
    float* out = (float*)d_out;
    char*  ws  = (char*)d_ws;

    float*     loss_accum = (float*)ws;
    float*     csq = (float*)(ws + 256);
    _Float16*  bhi = (_Float16*)(ws + 256 + 131072);
    _Float16*  blo = (_Float16*)(ws + 256 + 131072 + FRAG_HALVES * 2);

    hipLaunchKernelGGL(prep_csq,   dim3(128),  dim3(256), 0, stream, cb, csq);
    hipLaunchKernelGGL(prep_frags, dim3(2048), dim3(256), 0, stream, cb, bhi, blo, loss_accum);
    hipLaunchKernelGGL(rvq_main,   dim3(NBLK), dim3(256), 0, stream,
                       x, cb, bhi, blo, csq, out, loss_accum);
    hipLaunchKernelGGL(finish_loss, dim3(1), dim3(1), 0, stream, loss_accum, out);
}